// Round 1
// baseline (474.060 us; speedup 1.0000x reference)
//
#include <hip/hip_runtime.h>
#include <stdint.h>

namespace {

constexpr int kB = 32, kT = 576, kC = 1024, kH = 16, kD = 64;
constexpr int kM = kB * kT;        // 18432 rows
constexpr int kNqkv = 3 * kC;      // 3072

typedef uint16_t u16;
typedef __attribute__((ext_vector_type(4))) float f32x4;
typedef __attribute__((ext_vector_type(8))) short short8;
typedef __attribute__((ext_vector_type(8))) __bf16 bf16x8;
typedef __attribute__((ext_vector_type(4))) uint16_t u16x4;

__device__ __forceinline__ f32x4 mfma_bf16(short8 a, short8 b, f32x4 c) {
  return __builtin_amdgcn_mfma_f32_16x16x32_bf16(
      __builtin_bit_cast(bf16x8, a), __builtin_bit_cast(bf16x8, b), c, 0, 0, 0);
}

__device__ __forceinline__ u16 to_bf16(float x) {
  uint32_t u = __float_as_uint(x);
  u += 0x7fffu + ((u >> 16) & 1u);
  return (u16)(u >> 16);
}

__device__ __forceinline__ void gload_lds16(const void* g, void* l) {
  __builtin_amdgcn_global_load_lds(
      (const __attribute__((address_space(1))) uint32_t*)(uintptr_t)g,
      (__attribute__((address_space(3))) uint32_t*)(uintptr_t)l,
      16, 0, 0);
}

// ---- f32 -> bf16 flat cast (vectorized: 16B load / 8B store per lane) ----
__global__ __launch_bounds__(256) void cvt_bf16_kernel(
    const float* __restrict__ in, u16* __restrict__ out, int n4) {
  const int i = blockIdx.x * 256 + threadIdx.x;
  if (i >= n4) return;
  const f32x4 v = ((const f32x4*)in)[i];
  u16x4 o;
#pragma unroll
  for (int j = 0; j < 4; ++j) o[j] = to_bf16(v[j]);
  ((u16x4*)out)[i] = o;
}

// ---- transpose-convert: in[K][N] f32 -> out[N][K] bf16 ----
__global__ void tconv_kernel(const float* __restrict__ in, u16* __restrict__ out,
                             int K, int N) {
  __shared__ u16 tile[32][33];
  const int nb = blockIdx.x * 32;
  const int kb = blockIdx.y * 32;
  const int tx = threadIdx.x;   // 0..31
  const int ty = threadIdx.y;   // 0..7
#pragma unroll
  for (int i = 0; i < 32; i += 8)
    tile[ty + i][tx] = to_bf16(in[(size_t)(kb + ty + i) * N + nb + tx]);
  __syncthreads();
#pragma unroll
  for (int i = 0; i < 32; i += 8)
    out[(size_t)(nb + ty + i) * K + kb + tx] = tile[tx][ty + i];
}

// ---- GEMM: A[M,K] bf16 x Bt[N,K] bf16 (+bias).  128x128 tile, BK=32,
//      4 waves in 2x2, double-buffered LDS, global_load_lds width 16.
// MODE 0: QKV epilogue -> scatter to Q (pre-scaled 1/64), K [B,H,T,D], V^T [B,H,D,T]
// MODE 1: proj epilogue -> f32 out [M,N] + bias
template <int MODE, int Nc, int Kc>
__global__ __launch_bounds__(256) void gemm_bt(
    const u16* __restrict__ A, const u16* __restrict__ Bt,
    const float* __restrict__ bias, float* __restrict__ outF,
    u16* __restrict__ outQ, u16* __restrict__ outK, u16* __restrict__ outVT) {
  __shared__ u16 As[2][128 * 32];
  __shared__ u16 Bs[2][128 * 32];

  const int tid = threadIdx.x;
  const int wave = tid >> 6;
  const int lane = tid & 63;
  const int lo = lane & 15;
  const int hi = lane >> 4;
  const int wr = wave >> 1;   // wave row (0..1), 64 rows each
  const int wc = wave & 1;    // wave col (0..1), 64 cols each
  const int n0 = blockIdx.x * 128;
  const int m0 = blockIdx.y * 128;

  // staging geometry: tile is 128 rows x 32 cols bf16 = 8192B, rows of 64B.
  // wave w covers bytes [w*1024, w*1024+1024) (+4096 for second pass).
  const int so = wave * 1024 + lane * 16;   // byte offset in tile, pass 0
  const int srow = so >> 6;                 // tile row
  const int scol = (so & 63) >> 1;          // element col
  const u16* gA = A + (size_t)(m0 + srow) * Kc + scol;
  const u16* gB = Bt + (size_t)(n0 + srow) * Kc + scol;
  char* ldsA = (char*)&As[0][0];
  char* ldsB = (char*)&Bs[0][0];
  const int ldoff = wave * 1024;            // wave-uniform LDS base

  f32x4 acc[4][4] = {};

  auto stage = [&](int buf, int kt) {
    const int k0 = kt * 32;
    gload_lds16(gA + k0,           ldsA + buf * 8192 + ldoff);
    gload_lds16(gA + k0 + 64 * Kc, ldsA + buf * 8192 + ldoff + 4096);
    gload_lds16(gB + k0,           ldsB + buf * 8192 + ldoff);
    gload_lds16(gB + k0 + 64 * Kc, ldsB + buf * 8192 + ldoff + 4096);
  };

  stage(0, 0);
  __syncthreads();   // drains vmcnt before barrier (compiler semantics)

  constexpr int NT = Kc / 32;
  int buf = 0;
  for (int kt = 0; kt < NT; ++kt) {
    if (kt + 1 < NT) stage(buf ^ 1, kt + 1);
    short8 af[4], bfv[4];
#pragma unroll
    for (int i = 0; i < 4; ++i) {
      af[i]  = *(const short8*)&As[buf][(wr * 64 + i * 16 + lo) * 32 + hi * 8];
      bfv[i] = *(const short8*)&Bs[buf][(wc * 64 + i * 16 + lo) * 32 + hi * 8];
    }
#pragma unroll
    for (int i = 0; i < 4; ++i)
#pragma unroll
      for (int j = 0; j < 4; ++j)
        acc[i][j] = mfma_bf16(af[i], bfv[j], acc[i][j]);
    __syncthreads();
    buf ^= 1;
  }

  // epilogue.  C/D frag: col = lo, row = hi*4 + r   [verified m89/m91]
#pragma unroll
  for (int j = 0; j < 4; ++j) {
    const int n = n0 + wc * 64 + j * 16 + lo;
    const float bv = bias[n];
    if (MODE == 1) {
#pragma unroll
      for (int i = 0; i < 4; ++i) {
        const int mrow = m0 + wr * 64 + i * 16 + hi * 4;
#pragma unroll
        for (int r = 0; r < 4; ++r)
          outF[(size_t)(mrow + r) * Nc + n] = acc[i][j][r] + bv;
      }
    } else {
      const int which = n >> 10;       // block-uniform (128 | 1024)
      const int c = n & 1023;
      const int hh = c >> 6;
      const int d = c & 63;
#pragma unroll
      for (int i = 0; i < 4; ++i) {
        const int mrow = m0 + wr * 64 + i * 16 + hi * 4;
#pragma unroll
        for (int r = 0; r < 4; ++r) {
          const int m = mrow + r;
          const int bb = m / kT;
          const int t = m - bb * kT;
          const float v = acc[i][j][r] + bv;
          if (which == 0)       // Q, pre-scaled by 1/D
            outQ[((size_t)(bb * kH + hh) * kT + t) * kD + d] = to_bf16(v * (1.0f / 64.0f));
          else if (which == 1)  // K
            outK[((size_t)(bb * kH + hh) * kT + t) * kD + d] = to_bf16(v);
          else                  // V stored transposed [B,H,D,T]
            outVT[((size_t)(bb * kH + hh) * kD + d) * kT + t] = to_bf16(v);
        }
      }
    }
  }
}

// ---- causal flash attention.  Q pre-scaled by 1/D.
// grid (T/64, B*H), 4 waves/block, wave = 16 q-rows, KVBLK=32.
// Q,K [B,H,T,D] bf16; VT [B,H,D,T] bf16; Y out [B,T,H,D] bf16.
__global__ __launch_bounds__(256) void attn_kernel(
    const u16* __restrict__ Q, const u16* __restrict__ K,
    const u16* __restrict__ VT, u16* __restrict__ Y) {
  __shared__ u16 P[4][16][32];   // per-wave P tile (bf16)

  const int bh = blockIdx.y;
  const int qb = blockIdx.x * 64;
  const int wave = threadIdx.x >> 6;
  const int lane = threadIdx.x & 63;
  const int lo = lane & 15;
  const int hi = lane >> 4;
  const int q0 = qb + wave * 16;

  const u16* Qb = Q + (size_t)bh * kT * kD;
  const u16* Kb = K + (size_t)bh * kT * kD;
  const u16* Vb = VT + (size_t)bh * kD * kT;

  const u16* qp = Qb + (q0 + lo) * kD + hi * 8;
  const short8 qf0 = *(const short8*)qp;
  const short8 qf1 = *(const short8*)(qp + 32);

  f32x4 acc[4] = {};
  float mrun[4], lrun[4];
#pragma unroll
  for (int r = 0; r < 4; ++r) { mrun[r] = -3e38f; lrun[r] = 0.f; }

  const int kv_end = q0 + 16;          // causal bound for this wave
  for (int kv = 0; kv < kv_end; kv += 32) {
    f32x4 s[2];
#pragma unroll
    for (int kc = 0; kc < 2; ++kc) {
      const u16* kp = Kb + (kv + kc * 16 + lo) * kD + hi * 8;
      const short8 kf0 = *(const short8*)kp;
      const short8 kf1 = *(const short8*)(kp + 32);
      f32x4 z = {0.f, 0.f, 0.f, 0.f};
      z = mfma_bf16(qf0, kf0, z);
      z = mfma_bf16(qf1, kf1, z);
      s[kc] = z;
    }
    if (kv + 31 > q0) {   // diagonal tile: causal mask
#pragma unroll
      for (int kc = 0; kc < 2; ++kc)
#pragma unroll
        for (int r = 0; r < 4; ++r)
          if (kv + kc * 16 + lo > q0 + hi * 4 + r) s[kc][r] = -3e38f;
    }
    // per-row (r) max over the 16 score-columns held across the 16-lane group
    float pm[4], rs[4], corr[4];
#pragma unroll
    for (int r = 0; r < 4; ++r) pm[r] = fmaxf(s[0][r], s[1][r]);
#pragma unroll
    for (int off = 8; off >= 1; off >>= 1)
#pragma unroll
      for (int r = 0; r < 4; ++r) pm[r] = fmaxf(pm[r], __shfl_xor(pm[r], off));
#pragma unroll
    for (int r = 0; r < 4; ++r) {
      const float mnew = fmaxf(mrun[r], pm[r]);
      corr[r] = __expf(mrun[r] - mnew);
      mrun[r] = mnew;
    }
#pragma unroll
    for (int r = 0; r < 4; ++r) {
      const float p0 = __expf(s[0][r] - mrun[r]);
      const float p1 = __expf(s[1][r] - mrun[r]);
      rs[r] = p0 + p1;
      P[wave][hi * 4 + r][lo] = to_bf16(p0);
      P[wave][hi * 4 + r][16 + lo] = to_bf16(p1);
    }
#pragma unroll
    for (int off = 8; off >= 1; off >>= 1)
#pragma unroll
      for (int r = 0; r < 4; ++r) rs[r] += __shfl_xor(rs[r], off);
#pragma unroll
    for (int r = 0; r < 4; ++r) lrun[r] = lrun[r] * corr[r] + rs[r];
#pragma unroll
    for (int nt = 0; nt < 4; ++nt)
#pragma unroll
      for (int r = 0; r < 4; ++r) acc[nt][r] *= corr[r];

    // P transpose via wave-local LDS (in-order DS within a wave, no barrier)
    const short8 pf = *(const short8*)&P[wave][lo][hi * 8];
#pragma unroll
    for (int nt = 0; nt < 4; ++nt) {
      const short8 vf = *(const short8*)(Vb + (nt * 16 + lo) * kT + kv + hi * 8);
      acc[nt] = mfma_bf16(pf, vf, acc[nt]);
    }
  }

  const int b = bh >> 4, h = bh & 15;
#pragma unroll
  for (int r = 0; r < 4; ++r) {
    const float inv = 1.0f / lrun[r];
    const int t = q0 + hi * 4 + r;
    const size_t base = ((size_t)(b * kT + t) * kH + h) * kD;
#pragma unroll
    for (int nt = 0; nt < 4; ++nt)
      Y[base + nt * 16 + lo] = to_bf16(acc[nt][r] * inv);
  }
}

}  // namespace

extern "C" void kernel_launch(void* const* d_in, const int* in_sizes, int n_in,
                              void* d_out, int out_size, void* d_ws, size_t ws_size,
                              hipStream_t stream) {
  (void)in_sizes; (void)n_in; (void)out_size; (void)ws_size;
  const float* emb   = (const float*)d_in[0];
  const float* wqkv  = (const float*)d_in[1];
  const float* bqkv  = (const float*)d_in[2];
  const float* wproj = (const float*)d_in[3];
  const float* bproj = (const float*)d_in[4];
  float* out = (float*)d_out;

  // workspace layout (needs ~188 MB)
  char* p = (char*)d_ws;
  u16* embb   = (u16*)p; p += (size_t)kM * kC * 2;
  u16* wqkvt  = (u16*)p; p += (size_t)kNqkv * kC * 2;
  u16* wprojt = (u16*)p; p += (size_t)kC * kC * 2;
  u16* Qh     = (u16*)p; p += (size_t)kM * kC * 2;
  u16* Kh     = (u16*)p; p += (size_t)kM * kC * 2;
  u16* VTh    = (u16*)p; p += (size_t)kM * kC * 2;
  u16* Yh     = (u16*)p; p += (size_t)kM * kC * 2;

  const int n4 = kM * kC / 4;
  cvt_bf16_kernel<<<dim3((n4 + 255) / 256), 256, 0, stream>>>(emb, embb, n4);
  tconv_kernel<<<dim3(kNqkv / 32, kC / 32), dim3(32, 8), 0, stream>>>(wqkv, wqkvt, kC, kNqkv);
  tconv_kernel<<<dim3(kC / 32, kC / 32), dim3(32, 8), 0, stream>>>(wproj, wprojt, kC, kC);
  gemm_bt<0, kNqkv, kC><<<dim3(kNqkv / 128, kM / 128), 256, 0, stream>>>(
      embb, wqkvt, bqkv, nullptr, Qh, Kh, VTh);
  attn_kernel<<<dim3(kT / 64, kB * kH), 256, 0, stream>>>(Qh, Kh, VTh, Yh);
  gemm_bt<1, kC, kC><<<dim3(kC / 128, kM / 128), 256, 0, stream>>>(
      Yh, wprojt, bproj, out, nullptr, nullptr, nullptr);
}

// Round 2
// 459.617 us; speedup vs baseline: 1.0314x; 1.0314x over previous
//
#include <hip/hip_runtime.h>
#include <stdint.h>

namespace {

constexpr int kB = 32, kT = 576, kC = 1024, kH = 16, kD = 64;
constexpr int kM = kB * kT;        // 18432 rows
constexpr int kNqkv = 3 * kC;      // 3072

typedef uint16_t u16;
typedef __attribute__((ext_vector_type(4))) float f32x4;
typedef __attribute__((ext_vector_type(8))) short short8;
typedef __attribute__((ext_vector_type(8))) __bf16 bf16x8;
typedef __attribute__((ext_vector_type(4))) uint16_t u16x4;

__device__ __forceinline__ f32x4 mfma_bf16(short8 a, short8 b, f32x4 c) {
  return __builtin_amdgcn_mfma_f32_16x16x32_bf16(
      __builtin_bit_cast(bf16x8, a), __builtin_bit_cast(bf16x8, b), c, 0, 0, 0);
}

__device__ __forceinline__ u16 to_bf16(float x) {
  uint32_t u = __float_as_uint(x);
  u += 0x7fffu + ((u >> 16) & 1u);
  return (u16)(u >> 16);
}

__device__ __forceinline__ void gload_lds16(const void* g, void* l) {
  __builtin_amdgcn_global_load_lds(
      (const __attribute__((address_space(1))) uint32_t*)(uintptr_t)g,
      (__attribute__((address_space(3))) uint32_t*)(uintptr_t)l,
      16, 0, 0);
}

// raw barrier: no vmcnt drain (the whole point). Compiler fences pin
// LDS reads / global_load_lds issues on their side of the barrier.
__device__ __forceinline__ void bar() {
  asm volatile("" ::: "memory");
  __builtin_amdgcn_s_barrier();
  asm volatile("" ::: "memory");
}

// ---- f32 -> bf16 flat cast (vectorized: 16B load / 8B store per lane) ----
__global__ __launch_bounds__(256) void cvt_bf16_kernel(
    const float* __restrict__ in, u16* __restrict__ out, int n4) {
  const int i = blockIdx.x * 256 + threadIdx.x;
  if (i >= n4) return;
  const f32x4 v = ((const f32x4*)in)[i];
  u16x4 o;
#pragma unroll
  for (int j = 0; j < 4; ++j) o[j] = to_bf16(v[j]);
  ((u16x4*)out)[i] = o;
}

// ---- transpose-convert: in[K][N] f32 -> out[N][K] bf16 ----
__global__ void tconv_kernel(const float* __restrict__ in, u16* __restrict__ out,
                             int K, int N) {
  __shared__ u16 tile[32][33];
  const int nb = blockIdx.x * 32;
  const int kb = blockIdx.y * 32;
  const int tx = threadIdx.x;   // 0..31
  const int ty = threadIdx.y;   // 0..7
#pragma unroll
  for (int i = 0; i < 32; i += 8)
    tile[ty + i][tx] = to_bf16(in[(size_t)(kb + ty + i) * N + nb + tx]);
  __syncthreads();
#pragma unroll
  for (int i = 0; i < 32; i += 8)
    out[(size_t)(nb + ty + i) * K + kb + tx] = tile[tx][ty + i];
}

// ---- GEMM v2: counted-vmcnt ring-3 pipeline ----
// A[M,1024] bf16 x Bt[N,1024] bf16 (+bias).
// BM=256, BN=128, BK=64, 512 threads = 8 waves (2 Mrows x 4 Ncols).
// Per-wave output 128x32 -> acc[8][2] f32x4.
// LDS: 3 slots x (A 32KB + B 16KB) = 144 KB ring, prefetch distance 2.
// T2 swizzle: LDS tile rows are 128B; element at (row, colb) lives at
// colb ^ ((row&7)<<4). Staging keeps LDS dest linear and inverse-swizzles
// the per-lane GLOBAL source (rule 21); ds_reads apply the same XOR.
// T4: s_waitcnt vmcnt(12) steady-state (2 tiles x 6 loads in flight), never 0
// until the tail. T5: setprio around the MFMA cluster.
// MODE 0: QKV scatter epilogue (Q scaled 1/64, K, V^T). MODE 1: f32 +bias.
template <int MODE>
__global__ __launch_bounds__(512, 2) void gemm2(
    const u16* __restrict__ A, const u16* __restrict__ Bt,
    const float* __restrict__ bias, float* __restrict__ outF,
    u16* __restrict__ outQ, u16* __restrict__ outK, u16* __restrict__ outVT) {
  constexpr int Kc = 1024;
  constexpr int NT = Kc / 64;          // 16 K-tiles
  __shared__ char lds[3][49152];       // slot: A @0 (32KB), B @32768 (16KB)

  const int tid = threadIdx.x;
  const int wave = tid >> 6;
  const int lane = tid & 63;
  const int lo = lane & 15;
  const int hi = lane >> 4;
  const int wr = wave >> 2;            // 0..1 -> rows wr*128
  const int wc = wave & 3;             // 0..3 -> cols wc*32
  const int n0 = blockIdx.x * 128;
  const int m0 = blockIdx.y * 256;

  // Precompute per-lane staging sources (inverse-swizzled globals).
  const u16* srcA[4];
  const u16* srcB[2];
#pragma unroll
  for (int c = 0; c < 4; ++c) {
    const int b = c * 8192 + wave * 1024 + lane * 16;
    const int row = b >> 7;
    const int colb = (b & 127) ^ ((row & 7) << 4);
    srcA[c] = A + (size_t)(m0 + row) * Kc + (colb >> 1);
  }
#pragma unroll
  for (int c = 0; c < 2; ++c) {
    const int b = c * 8192 + wave * 1024 + lane * 16;
    const int row = b >> 7;
    const int colb = (b & 127) ^ ((row & 7) << 4);
    srcB[c] = Bt + (size_t)(n0 + row) * Kc + (colb >> 1);
  }

  auto stage = [&](int slot, int t) {       // 6 global_load_lds per thread
    const int k0 = t * 64;
    char* base = &lds[slot][0];
#pragma unroll
    for (int c = 0; c < 4; ++c)
      gload_lds16(srcA[c] + k0, base + c * 8192 + wave * 1024);
#pragma unroll
    for (int c = 0; c < 2; ++c)
      gload_lds16(srcB[c] + k0, base + 32768 + c * 8192 + wave * 1024);
  };

  f32x4 acc[8][2] = {};

  auto compute = [&](int slot) {
    const char* base = &lds[slot][0];
    __builtin_amdgcn_s_setprio(1);
#pragma unroll
    for (int ks = 0; ks < 2; ++ks) {
      const int cb = (ks * 64 + hi * 16) ^ ((lo & 7) << 4);
      short8 af[8], bfv[2];
#pragma unroll
      for (int i = 0; i < 8; ++i)
        af[i] = *(const short8*)(base + (wr * 128 + i * 16 + lo) * 128 + cb);
#pragma unroll
      for (int j = 0; j < 2; ++j)
        bfv[j] = *(const short8*)(base + 32768 + (wc * 32 + j * 16 + lo) * 128 + cb);
#pragma unroll
      for (int i = 0; i < 8; ++i)
#pragma unroll
        for (int j = 0; j < 2; ++j)
          acc[i][j] = mfma_bf16(af[i], bfv[j], acc[i][j]);
    }
    __builtin_amdgcn_s_setprio(0);
  };

  // Pipeline. stage(t+2) in iter t overwrites slot((t-1)%3): its readers all
  // passed iter t-1's closing barrier before any wave issues this stage.
  stage(0, 0);
  stage(1, 1);
  for (int t = 0; t < NT - 2; ++t) {
    stage((t + 2) % 3, t + 2);
    asm volatile("s_waitcnt vmcnt(12)" ::: "memory");  // own tile-t loads done
    bar();                                             // everyone's done
    compute(t % 3);
    bar();                                             // tile t consumed
  }
  asm volatile("s_waitcnt vmcnt(6)" ::: "memory");
  bar();
  compute((NT - 2) % 3);
  bar();
  asm volatile("s_waitcnt vmcnt(0)" ::: "memory");
  bar();
  compute((NT - 1) % 3);

  // Epilogue. C/D frag: col = lo, row = hi*4 + r   [m89/m91]
#pragma unroll
  for (int j = 0; j < 2; ++j) {
    const int n = n0 + wc * 32 + j * 16 + lo;
    const float bv = bias[n];
    if (MODE == 1) {
#pragma unroll
      for (int i = 0; i < 8; ++i) {
        const int mrow = m0 + wr * 128 + i * 16 + hi * 4;
#pragma unroll
        for (int r = 0; r < 4; ++r)
          outF[(size_t)(mrow + r) * kC + n] = acc[i][j][r] + bv;
      }
    } else {
      const int which = n >> 10;       // block-uniform (1024 % 128 == 0)
      const int c = n & 1023;
      const int hh = c >> 6;
      const int d = c & 63;
#pragma unroll
      for (int i = 0; i < 8; ++i) {
        const int mrow = m0 + wr * 128 + i * 16 + hi * 4;
#pragma unroll
        for (int r = 0; r < 4; ++r) {
          const int m = mrow + r;
          const int bb = m / kT;
          const int t = m - bb * kT;
          const float v = acc[i][j][r] + bv;
          if (which == 0)       // Q, pre-scaled by 1/D
            outQ[((size_t)(bb * kH + hh) * kT + t) * kD + d] = to_bf16(v * (1.0f / 64.0f));
          else if (which == 1)  // K
            outK[((size_t)(bb * kH + hh) * kT + t) * kD + d] = to_bf16(v);
          else                  // V stored transposed [B,H,D,T]
            outVT[((size_t)(bb * kH + hh) * kD + d) * kT + t] = to_bf16(v);
        }
      }
    }
  }
}

// ---- causal flash attention.  Q pre-scaled by 1/D.
// grid (T/64, B*H), 4 waves/block, wave = 16 q-rows, KVBLK=32.
// Q,K [B,H,T,D] bf16; VT [B,H,D,T] bf16; Y out [B,T,H,D] bf16.
__global__ __launch_bounds__(256) void attn_kernel(
    const u16* __restrict__ Q, const u16* __restrict__ K,
    const u16* __restrict__ VT, u16* __restrict__ Y) {
  __shared__ u16 P[4][16][32];   // per-wave P tile (bf16)

  const int bh = blockIdx.y;
  const int qb = blockIdx.x * 64;
  const int wave = threadIdx.x >> 6;
  const int lane = threadIdx.x & 63;
  const int lo = lane & 15;
  const int hi = lane >> 4;
  const int q0 = qb + wave * 16;

  const u16* Qb = Q + (size_t)bh * kT * kD;
  const u16* Kb = K + (size_t)bh * kT * kD;
  const u16* Vb = VT + (size_t)bh * kD * kT;

  const u16* qp = Qb + (q0 + lo) * kD + hi * 8;
  const short8 qf0 = *(const short8*)qp;
  const short8 qf1 = *(const short8*)(qp + 32);

  f32x4 acc[4] = {};
  float mrun[4], lrun[4];
#pragma unroll
  for (int r = 0; r < 4; ++r) { mrun[r] = -3e38f; lrun[r] = 0.f; }

  const int kv_end = q0 + 16;          // causal bound for this wave
  for (int kv = 0; kv < kv_end; kv += 32) {
    f32x4 s[2];
#pragma unroll
    for (int kc = 0; kc < 2; ++kc) {
      const u16* kp = Kb + (kv + kc * 16 + lo) * kD + hi * 8;
      const short8 kf0 = *(const short8*)kp;
      const short8 kf1 = *(const short8*)(kp + 32);
      f32x4 z = {0.f, 0.f, 0.f, 0.f};
      z = mfma_bf16(qf0, kf0, z);
      z = mfma_bf16(qf1, kf1, z);
      s[kc] = z;
    }
    if (kv + 31 > q0) {   // diagonal tile: causal mask
#pragma unroll
      for (int kc = 0; kc < 2; ++kc)
#pragma unroll
        for (int r = 0; r < 4; ++r)
          if (kv + kc * 16 + lo > q0 + hi * 4 + r) s[kc][r] = -3e38f;
    }
    // per-row (r) max over the 16 score-columns held across the 16-lane group
    float pm[4], rs[4], corr[4];
#pragma unroll
    for (int r = 0; r < 4; ++r) pm[r] = fmaxf(s[0][r], s[1][r]);
#pragma unroll
    for (int off = 8; off >= 1; off >>= 1)
#pragma unroll
      for (int r = 0; r < 4; ++r) pm[r] = fmaxf(pm[r], __shfl_xor(pm[r], off));
#pragma unroll
    for (int r = 0; r < 4; ++r) {
      const float mnew = fmaxf(mrun[r], pm[r]);
      corr[r] = __expf(mrun[r] - mnew);
      mrun[r] = mnew;
    }
#pragma unroll
    for (int r = 0; r < 4; ++r) {
      const float p0 = __expf(s[0][r] - mrun[r]);
      const float p1 = __expf(s[1][r] - mrun[r]);
      rs[r] = p0 + p1;
      P[wave][hi * 4 + r][lo] = to_bf16(p0);
      P[wave][hi * 4 + r][16 + lo] = to_bf16(p1);
    }
#pragma unroll
    for (int off = 8; off >= 1; off >>= 1)
#pragma unroll
      for (int r = 0; r < 4; ++r) rs[r] += __shfl_xor(rs[r], off);
#pragma unroll
    for (int r = 0; r < 4; ++r) lrun[r] = lrun[r] * corr[r] + rs[r];
#pragma unroll
    for (int nt = 0; nt < 4; ++nt)
#pragma unroll
      for (int r = 0; r < 4; ++r) acc[nt][r] *= corr[r];

    // P transpose via wave-local LDS (in-order DS within a wave, no barrier)
    const short8 pf = *(const short8*)&P[wave][lo][hi * 8];
#pragma unroll
    for (int nt = 0; nt < 4; ++nt) {
      const short8 vf = *(const short8*)(Vb + (nt * 16 + lo) * kT + kv + hi * 8);
      acc[nt] = mfma_bf16(pf, vf, acc[nt]);
    }
  }

  const int b = bh >> 4, h = bh & 15;
#pragma unroll
  for (int r = 0; r < 4; ++r) {
    const float inv = 1.0f / lrun[r];
    const int t = q0 + hi * 4 + r;
    const size_t base = ((size_t)(b * kT + t) * kH + h) * kD;
#pragma unroll
    for (int nt = 0; nt < 4; ++nt)
      Y[base + nt * 16 + lo] = to_bf16(acc[nt][r] * inv);
  }
}

}  // namespace

extern "C" void kernel_launch(void* const* d_in, const int* in_sizes, int n_in,
                              void* d_out, int out_size, void* d_ws, size_t ws_size,
                              hipStream_t stream) {
  (void)in_sizes; (void)n_in; (void)out_size; (void)ws_size;
  const float* emb   = (const float*)d_in[0];
  const float* wqkv  = (const float*)d_in[1];
  const float* bqkv  = (const float*)d_in[2];
  const float* wproj = (const float*)d_in[3];
  const float* bproj = (const float*)d_in[4];
  float* out = (float*)d_out;

  // workspace layout (needs ~188 MB)
  char* p = (char*)d_ws;
  u16* embb   = (u16*)p; p += (size_t)kM * kC * 2;
  u16* wqkvt  = (u16*)p; p += (size_t)kNqkv * kC * 2;
  u16* wprojt = (u16*)p; p += (size_t)kC * kC * 2;
  u16* Qh     = (u16*)p; p += (size_t)kM * kC * 2;
  u16* Kh     = (u16*)p; p += (size_t)kM * kC * 2;
  u16* VTh    = (u16*)p; p += (size_t)kM * kC * 2;
  u16* Yh     = (u16*)p; p += (size_t)kM * kC * 2;

  const int n4 = kM * kC / 4;
  cvt_bf16_kernel<<<dim3((n4 + 255) / 256), 256, 0, stream>>>(emb, embb, n4);
  tconv_kernel<<<dim3(kNqkv / 32, kC / 32), dim3(32, 8), 0, stream>>>(wqkv, wqkvt, kC, kNqkv);
  tconv_kernel<<<dim3(kC / 32, kC / 32), dim3(32, 8), 0, stream>>>(wproj, wprojt, kC, kC);
  gemm2<0><<<dim3(kNqkv / 128, kM / 256), 512, 0, stream>>>(
      embb, wqkvt, bqkv, nullptr, Qh, Kh, VTh);
  attn_kernel<<<dim3(kT / 64, kB * kH), 256, 0, stream>>>(Qh, Kh, VTh, Yh);
  gemm2<1><<<dim3(kC / 128, kM / 256), 512, 0, stream>>>(
      Yh, wprojt, bproj, out, nullptr, nullptr, nullptr);
}